// Round 1
// baseline (1224.632 us; speedup 1.0000x reference)
//
#include <hip/hip_runtime.h>
#include <stdint.h>

// EdgeConv fused: out[i] = max over edges (j->i) of MLP3(concat[x_i, x_j-x_i])
// Layer-1 split: e@W1 = x_i@(W1a-W1b) + x_j@W1b  (W1a=W1[0:128], W1b=W1[128:256])
// Per-node precompute a=x@(W1a-W1b)+b1, c=x@W1b (bf16). Per-edge: h1=relu(a[dst]+c[src]),
// then two bf16-MFMA GEMMs (transposed chain) + coalesced atomic-max scatter.

#define N_NODES 50000
#define N_EDGES 800000

typedef __attribute__((ext_vector_type(4))) float f32x4;
typedef __attribute__((ext_vector_type(8))) short s16x8;
typedef __attribute__((ext_vector_type(4))) unsigned int u32x4;
typedef __attribute__((ext_vector_type(2))) unsigned int u32x2;

__device__ __forceinline__ float bf2f(unsigned int b){ return __builtin_bit_cast(float, b << 16); }
__device__ __forceinline__ unsigned int f2bf(float f){          // RNE f32->bf16, returns in low 16
  unsigned int u = __builtin_bit_cast(unsigned int, f);
  return (u + 0x7FFFu + ((u >> 16) & 1u)) >> 16;
}
__device__ __forceinline__ unsigned int pk2(float lo, float hi){ return f2bf(lo) | (f2bf(hi) << 16); }
// monotone float->uint map: f1<f2 <=> map(f1)<map(f2); min possible valid value > 0
__device__ __forceinline__ unsigned int fmap(float f){
  unsigned int u = __builtin_bit_cast(unsigned int, f);
  return (u & 0x80000000u) ? ~u : (u | 0x80000000u);
}

// ---- detect edge_index element width: int64 (odd u32 slots all zero) vs int32 ----
extern "C" __global__ void k_detect(const unsigned int* __restrict__ e, int* __restrict__ flag){
  unsigned int v = e[2 * threadIdx.x + 1];
  unsigned long long b = __ballot(v != 0u);
  if (threadIdx.x == 0) *flag = (b == 0ull) ? 1 : 0;   // 1 => int64
}

// ---- pre-swizzle W2^T / W3^T into MFMA A-frag order, bf16 ----
// A-frag (16x16x32): lane l holds A[m=16*mfG+(l&15)][k=32*ks+8*(l>>4)+j], j=0..7
// storage: block (mfG*8+ks) of 64 lanes x 16B, fully coalesced on load.
extern "C" __global__ void k_wswz(const float* __restrict__ W2, const float* __restrict__ W3,
                                  unsigned short* __restrict__ w2s, unsigned short* __restrict__ w3s){
  int t = blockIdx.x * 256 + threadIdx.x;              // 0..16383
  const float* W = (t & 8192) ? W3 : W2;
  unsigned short* o = (t & 8192) ? w3s : w2s;
  int r = t & 8191;
  int lane = r & 63, blk = r >> 6;
  int mfG = blk >> 3, ks = blk & 7;
  int m  = mfG * 16 + (lane & 15);
  int k0 = ks * 32 + (lane >> 4) * 8;
  u32x4 ov;
  #pragma unroll
  for (int j = 0; j < 4; j++){
    unsigned int lo = f2bf(W[(size_t)(k0 + 2*j    ) * 256 + m]);   // A[m][k] = W[k][m]
    unsigned int hi = f2bf(W[(size_t)(k0 + 2*j + 1) * 256 + m]);
    ov[j] = lo | (hi << 16);
  }
  *(u32x4*)(o + (size_t)r * 8) = ov;
}

// ---- per-node precompute: a = x@(W1a-W1b)+b1, c = x@W1b  (fp32 math, bf16 out) ----
extern "C" __global__ void __launch_bounds__(512) k_ac(
    const float* __restrict__ x, const float* __restrict__ W1, const float* __restrict__ b1,
    unsigned short* __restrict__ a, unsigned short* __restrict__ cc){
  __shared__ float xs[128][8];                         // x-tile transposed [k][node]
  const int t = threadIdx.x;
  const int n0 = blockIdx.x * 8;
  #pragma unroll
  for (int i = t; i < 1024; i += 512){
    int r = i >> 7, k = i & 127;
    xs[k][r] = x[(size_t)(n0 + r) * 128 + k];
  }
  __syncthreads();
  const int col = t & 255, half = t >> 8;              // half 0 -> a, 1 -> c (wave-uniform)
  float acc[8] = {0.f,0.f,0.f,0.f,0.f,0.f,0.f,0.f};
  const float* wb = W1 + 128 * 256 + col;              // W1b column
  #pragma unroll 4
  for (int k = 0; k < 128; k++){
    float wv = wb[(size_t)k * 256];
    if (half == 0) wv = W1[(size_t)k * 256 + col] - wv;
    f32x4 xa = *(const f32x4*)&xs[k][0];
    f32x4 xb = *(const f32x4*)&xs[k][4];
    acc[0] += xa[0] * wv; acc[1] += xa[1] * wv; acc[2] += xa[2] * wv; acc[3] += xa[3] * wv;
    acc[4] += xb[0] * wv; acc[5] += xb[1] * wv; acc[6] += xb[2] * wv; acc[7] += xb[3] * wv;
  }
  float bias = (half == 0) ? b1[col] : 0.f;
  unsigned short* o = (half == 0) ? a : cc;
  #pragma unroll
  for (int r = 0; r < 8; r++)
    o[(size_t)(n0 + r) * 256 + col] = (unsigned short)f2bf(acc[r] + bias);
}

// ---- fused edge MLP: 64 edges/block, 4 waves; transposed MFMA chain ----
// LDS swizzle everywhere: byte ^= (row&7)<<4  (kills 512B-stride bank conflicts)
extern "C" __global__ void __launch_bounds__(256) k_edge(
    const unsigned short* __restrict__ a, const unsigned short* __restrict__ c,
    const s16x8* __restrict__ w2f, const s16x8* __restrict__ w3f,
    const float* __restrict__ b2, const float* __restrict__ b3,
    const void* __restrict__ eidx, const int* __restrict__ flag,
    unsigned int* __restrict__ outu){
  __shared__ unsigned char sm[65536];   // h1[64][256]bf16 | h2[64][256]bf16 ; overlaid by h3[64][256]f32
  __shared__ int dstI[64];
  __shared__ int srcI[64];
  const int tid = threadIdx.x;
  const int lane = tid & 63;
  const int w = tid >> 6;
  const int e0 = blockIdx.x * 64;

  if (tid < 64){
    int s, d;
    if (*flag){
      const long long* p = (const long long*)eidx;
      s = (int)p[e0 + tid]; d = (int)p[N_EDGES + e0 + tid];
    } else {
      const int* p = (const int*)eidx;
      s = p[e0 + tid]; d = p[N_EDGES + e0 + tid];
    }
    srcI[tid] = s; dstI[tid] = d;
  }
  __syncthreads();

  { // gather: h1 = relu(a[dst] + c[src])  -> sm[0:32K) bf16 swizzled
    const int e = tid >> 2, q = tid & 3;
    const unsigned short* pa = a + (size_t)dstI[e] * 256 + q * 64;
    const unsigned short* pc = c + (size_t)srcI[e] * 256 + q * 64;
    unsigned char* rowp = sm + e * 512;
    const int sw = (e & 7) << 4;
    #pragma unroll
    for (int j = 0; j < 8; j++){
      u32x4 ua = *(const u32x4*)(pa + j * 8);
      u32x4 uc = *(const u32x4*)(pc + j * 8);
      u32x4 ov;
      #pragma unroll
      for (int t2 = 0; t2 < 4; t2++){
        float lo = bf2f(ua[t2] & 0xFFFFu) + bf2f(uc[t2] & 0xFFFFu);
        float hi = bf2f(ua[t2] >> 16)     + bf2f(uc[t2] >> 16);
        ov[t2] = pk2(fmaxf(lo, 0.f), fmaxf(hi, 0.f));
      }
      *(u32x4*)(rowp + ((q * 128 + j * 16) ^ sw)) = ov;
    }
  }
  __syncthreads();

  const int lm = lane & 15, g = lane >> 4;
  f32x4 acc[4][4];
  #pragma unroll
  for (int mf = 0; mf < 4; mf++)
    #pragma unroll
    for (int nf = 0; nf < 4; nf++) acc[mf][nf] = (f32x4){0.f, 0.f, 0.f, 0.f};

  // G1: h2^T = W2^T @ h1^T   (A from pre-swizzled global, B from LDS)
  #pragma unroll
  for (int ks = 0; ks < 8; ks++){
    s16x8 af[4], bf[4];
    #pragma unroll
    for (int mf = 0; mf < 4; mf++) af[mf] = w2f[((w * 4 + mf) * 8 + ks) * 64 + lane];
    #pragma unroll
    for (int nf = 0; nf < 4; nf++){
      int row = nf * 16 + lm;
      bf[nf] = *(const s16x8*)(sm + row * 512 + ((ks * 64 + g * 16) ^ ((row & 7) << 4)));
    }
    #pragma unroll
    for (int mf = 0; mf < 4; mf++)
      #pragma unroll
      for (int nf = 0; nf < 4; nf++)
        acc[mf][nf] = __builtin_amdgcn_mfma_f32_16x16x32_bf16(af[mf], bf[nf], acc[mf][nf], 0, 0, 0);
  }

  { // bias2 + relu -> h2 bf16 swizzled at sm+32K (lane holds 4 consecutive channels: b64 packed write)
    #pragma unroll
    for (int mf = 0; mf < 4; mf++){
      const int m0 = w * 64 + mf * 16 + g * 4;
      const f32x4 bb = *(const f32x4*)(b2 + m0);
      #pragma unroll
      for (int nf = 0; nf < 4; nf++){
        int row = nf * 16 + lm;
        float v0 = fmaxf(acc[mf][nf][0] + bb[0], 0.f);
        float v1 = fmaxf(acc[mf][nf][1] + bb[1], 0.f);
        float v2 = fmaxf(acc[mf][nf][2] + bb[2], 0.f);
        float v3 = fmaxf(acc[mf][nf][3] + bb[3], 0.f);
        u32x2 pv = { pk2(v0, v1), pk2(v2, v3) };
        *(u32x2*)(sm + 32768 + row * 512 + ((m0 * 2) ^ ((row & 7) << 4))) = pv;
      }
    }
  }
  __syncthreads();

  // G2: h3^T = W3^T @ h2^T
  #pragma unroll
  for (int mf = 0; mf < 4; mf++)
    #pragma unroll
    for (int nf = 0; nf < 4; nf++) acc[mf][nf] = (f32x4){0.f, 0.f, 0.f, 0.f};
  #pragma unroll
  for (int ks = 0; ks < 8; ks++){
    s16x8 af[4], bf[4];
    #pragma unroll
    for (int mf = 0; mf < 4; mf++) af[mf] = w3f[((w * 4 + mf) * 8 + ks) * 64 + lane];
    #pragma unroll
    for (int nf = 0; nf < 4; nf++){
      int row = nf * 16 + lm;
      bf[nf] = *(const s16x8*)(sm + 32768 + row * 512 + ((ks * 64 + g * 16) ^ ((row & 7) << 4)));
    }
    #pragma unroll
    for (int mf = 0; mf < 4; mf++)
      #pragma unroll
      for (int nf = 0; nf < 4; nf++)
        acc[mf][nf] = __builtin_amdgcn_mfma_f32_16x16x32_bf16(af[mf], bf[nf], acc[mf][nf], 0, 0, 0);
  }
  __syncthreads();   // all h2 reads done before h3 (f32, 64KB) overlays h1+h2

  { // bias3 (no relu) -> h3 f32 swizzled, full 64KB
    #pragma unroll
    for (int mf = 0; mf < 4; mf++){
      const int m0 = w * 64 + mf * 16 + g * 4;
      const f32x4 bb = *(const f32x4*)(b3 + m0);
      #pragma unroll
      for (int nf = 0; nf < 4; nf++){
        int row = nf * 16 + lm;
        f32x4 v = { acc[mf][nf][0] + bb[0], acc[mf][nf][1] + bb[1],
                    acc[mf][nf][2] + bb[2], acc[mf][nf][3] + bb[3] };
        *(f32x4*)(sm + row * 1024 + ((m0 * 4) ^ ((row & 7) << 4))) = v;
      }
    }
  }
  __syncthreads();

  // coalesced atomic-max scatter: one 1KB-contiguous burst per edge row
  for (int it = 0; it < 64; it++){
    float v = *(const float*)(sm + it * 1024 + ((tid * 4) ^ ((it & 7) << 4)));
    unsigned int mu = fmap(v);
    unsigned int* p = outu + (size_t)dstI[it] * 256 + tid;
    if (mu > *p) atomicMax(p, mu);     // read-test safe: cell only grows; stale read => extra atomic
  }
}

// ---- unmap uint->float; untouched (0) cells = empty segments -> 0.0 ----
extern "C" __global__ void k_fix(unsigned int* __restrict__ o){
  size_t i = (size_t)blockIdx.x * 256 + threadIdx.x;
  unsigned int u = o[i];
  o[i] = (u == 0u) ? 0u : ((u & 0x80000000u) ? (u ^ 0x80000000u) : ~u);
}

extern "C" void kernel_launch(void* const* d_in, const int* in_sizes, int n_in,
                              void* d_out, int out_size, void* d_ws, size_t ws_size,
                              hipStream_t stream){
  const float* x  = (const float*)d_in[0];
  const void*  ei = d_in[1];
  const float* W1 = (const float*)d_in[2];
  const float* b1 = (const float*)d_in[3];
  const float* W2 = (const float*)d_in[4];
  const float* b2 = (const float*)d_in[5];
  const float* W3 = (const float*)d_in[6];
  const float* b3 = (const float*)d_in[7];

  const size_t A_BYTES = (size_t)N_NODES * 256 * 2;   // 25.6 MB each for a, c
  const size_t W_BYTES = 256 * 256 * 2;               // 128 KB each swizzled weight
  char* ws = (char*)d_ws;
  unsigned short* a   = (unsigned short*)(ws);
  unsigned short* cc  = (unsigned short*)(ws + A_BYTES);
  unsigned short* w2s = (unsigned short*)(ws + 2 * A_BYTES);
  unsigned short* w3s = (unsigned short*)(ws + 2 * A_BYTES + W_BYTES);
  int* flag           = (int*)(ws + 2 * A_BYTES + 2 * W_BYTES);
  if (ws_size < 2 * A_BYTES + 2 * W_BYTES + 16) return;   // insufficient scratch

  k_detect<<<1, 64, 0, stream>>>((const unsigned int*)ei, flag);
  k_wswz<<<64, 256, 0, stream>>>(W2, W3, w2s, w3s);
  k_ac<<<N_NODES / 8, 512, 0, stream>>>(x, W1, b1, a, cc);
  hipMemsetAsync(d_out, 0, (size_t)out_size * 4, stream);
  k_edge<<<N_EDGES / 64, 256, 0, stream>>>(a, cc, (const s16x8*)w2s, (const s16x8*)w3s,
                                           b2, b3, ei, flag, (unsigned int*)d_out);
  k_fix<<<(out_size + 255) / 256, 256, 0, stream>>>((unsigned int*)d_out);
}